// Round 1
// baseline (73.712 us; speedup 1.0000x reference)
//
#include <hip/hip_runtime.h>

// CenterLoss: loss = (1/B) * sum_b clip(||x_b - c_{l_b}||^2, 1e-12, 1e12)
//             + (C-1)*1e-12   (masked zeros clamped up to 1e-12 by reference)
//
// x: [B=8192, D=256] f32, labels: [B] int, centers: [C=10000, D=256] f32.
// One wave per sample: D=256 = 64 lanes x float4. Deterministic 2-kernel
// reduction (block partials in d_ws, then single-block finish).

#define NBLOCKS 256
#define TPB 256
#define WAVES_PER_BLOCK (TPB / 64)

__global__ __launch_bounds__(TPB) void centerloss_partial(
    const float* __restrict__ x,
    const int* __restrict__ labels,
    const float* __restrict__ centers,
    float* __restrict__ partial,
    int B)
{
    const int lane   = threadIdx.x & 63;
    const int wave   = (blockIdx.x * TPB + threadIdx.x) >> 6;
    const int nwaves = (gridDim.x * TPB) >> 6;

    float acc = 0.0f;
    for (int b = wave; b < B; b += nwaves) {
        const int lbl = labels[b];                       // wave-uniform load
        const float4 xv = ((const float4*)(x       + (size_t)b   * 256))[lane];
        const float4 cv = ((const float4*)(centers + (size_t)lbl * 256))[lane];

        // per-lane contribution to ||x||^2 + ||c||^2 - 2<x,c>
        float v = xv.x * xv.x + xv.y * xv.y + xv.z * xv.z + xv.w * xv.w;
        v += cv.x * cv.x + cv.y * cv.y + cv.z * cv.z + cv.w * cv.w;
        v -= 2.0f * (xv.x * cv.x + xv.y * cv.y + xv.z * cv.z + xv.w * cv.w);

        // wave-level sum (64 lanes)
        #pragma unroll
        for (int off = 32; off > 0; off >>= 1)
            v += __shfl_down(v, off, 64);

        if (lane == 0)
            acc += fminf(fmaxf(v, 1e-12f), 1e12f);
    }

    __shared__ float s[WAVES_PER_BLOCK];
    if (lane == 0) s[threadIdx.x >> 6] = acc;
    __syncthreads();
    if (threadIdx.x == 0) {
        float t = 0.0f;
        #pragma unroll
        for (int i = 0; i < WAVES_PER_BLOCK; ++i) t += s[i];
        partial[blockIdx.x] = t;
    }
}

__global__ __launch_bounds__(NBLOCKS) void centerloss_final(
    const float* __restrict__ partial,
    float* __restrict__ out,
    int B, int C)
{
    float v = partial[threadIdx.x];          // NBLOCKS == blockDim.x == 256
    #pragma unroll
    for (int off = 32; off > 0; off >>= 1)
        v += __shfl_down(v, off, 64);

    __shared__ float s[NBLOCKS / 64];
    if ((threadIdx.x & 63) == 0) s[threadIdx.x >> 6] = v;
    __syncthreads();
    if (threadIdx.x == 0) {
        float t = 0.0f;
        #pragma unroll
        for (int i = 0; i < NBLOCKS / 64; ++i) t += s[i];
        double loss = (double)t / (double)B + (double)(C - 1) * 1e-12;
        out[0] = (float)loss;
    }
}

extern "C" void kernel_launch(void* const* d_in, const int* in_sizes, int n_in,
                              void* d_out, int out_size, void* d_ws, size_t ws_size,
                              hipStream_t stream)
{
    const float* x       = (const float*)d_in[0];
    const int*   labels  = (const int*)d_in[1];
    const float* centers = (const float*)d_in[2];

    const int B = in_sizes[1];                 // 8192
    const int D = in_sizes[0] / B;             // 256 (layout assumed by kernel)
    const int C = in_sizes[2] / D;             // 10000
    (void)D;

    float* partial = (float*)d_ws;             // NBLOCKS floats of scratch
    float* out     = (float*)d_out;

    centerloss_partial<<<NBLOCKS, TPB, 0, stream>>>(x, labels, centers, partial, B);
    centerloss_final<<<1, NBLOCKS, 0, stream>>>(partial, out, B, C);
}

// Round 2
// 69.232 us; speedup vs baseline: 1.0647x; 1.0647x over previous
//
#include <hip/hip_runtime.h>

// CenterLoss: loss = (1/B) * sum_b clip(||x_b - c_{l_b}||^2, 1e-12, 1e12)
//             + (C-1)*1e-12   (reference clamps the B*(C-1) masked zeros up
//             to 1e-12 before summing; exact, though far below tolerance)
//
// x: [B=8192, D=256] f32, labels: [B] int, centers: [C=10000, D=256] f32.
//
// R2 design: ONE SAMPLE PER WAVE (8192 waves = 1024 blocks x 512 thr
// = 8 waves/SIMD, max occupancy) so the label->gathered-center dependent
// load chain (~1800 cy) is hidden by TLP instead of serialized 8x per wave
// as in R1 (which ran at 1 wave/SIMD). Each wave writes its own partial to
// d_ws; a second 1-block kernel reduces the B partials. Deterministic, no
// atomics (d_ws/d_out are poisoned 0xAA so atomic-accumulate would need an
// extra init anyway).

#define TPB1 512                 // 8 waves per block
#define TPB2 1024                // reduction block

__global__ __launch_bounds__(TPB1) void centerloss_partial(
    const float* __restrict__ x,
    const int* __restrict__ labels,
    const float* __restrict__ centers,
    float* __restrict__ partial,
    int B)
{
    const int lane = threadIdx.x & 63;
    const int b    = (blockIdx.x * TPB1 + threadIdx.x) >> 6;  // global wave id
    if (b >= B) return;

    const int lbl = labels[b];                                // wave-uniform
    const float4 xv = ((const float4*)(x       + (size_t)b   * 256))[lane];
    const float4 cv = ((const float4*)(centers + (size_t)lbl * 256))[lane];

    // per-lane contribution to ||x||^2 + ||c||^2 - 2<x,c>
    float v = xv.x * xv.x + xv.y * xv.y + xv.z * xv.z + xv.w * xv.w;
    v += cv.x * cv.x + cv.y * cv.y + cv.z * cv.z + cv.w * cv.w;
    v -= 2.0f * (xv.x * cv.x + xv.y * cv.y + xv.z * cv.z + xv.w * cv.w);

    // wave-level sum (64 lanes)
    #pragma unroll
    for (int off = 32; off > 0; off >>= 1)
        v += __shfl_down(v, off, 64);

    if (lane == 0)
        partial[b] = fminf(fmaxf(v, 1e-12f), 1e12f);
}

__global__ __launch_bounds__(TPB2) void centerloss_final(
    const float* __restrict__ partial,
    float* __restrict__ out,
    int n, int B, int C)
{
    float v = 0.0f;
    for (int i = threadIdx.x; i < n; i += TPB2)   // coalesced strided sums
        v += partial[i];

    #pragma unroll
    for (int off = 32; off > 0; off >>= 1)
        v += __shfl_down(v, off, 64);

    __shared__ float s[TPB2 / 64];
    if ((threadIdx.x & 63) == 0) s[threadIdx.x >> 6] = v;
    __syncthreads();
    if (threadIdx.x == 0) {
        float t = 0.0f;
        #pragma unroll
        for (int i = 0; i < TPB2 / 64; ++i) t += s[i];
        double loss = (double)t / (double)B + (double)(C - 1) * 1e-12;
        out[0] = (float)loss;
    }
}

extern "C" void kernel_launch(void* const* d_in, const int* in_sizes, int n_in,
                              void* d_out, int out_size, void* d_ws, size_t ws_size,
                              hipStream_t stream)
{
    const float* x       = (const float*)d_in[0];
    const int*   labels  = (const int*)d_in[1];
    const float* centers = (const float*)d_in[2];

    const int B = in_sizes[1];                 // 8192
    const int D = in_sizes[0] / B;             // 256 (layout assumed by kernel)
    const int C = in_sizes[2] / D;             // 10000

    float* partial = (float*)d_ws;             // B floats of scratch
    float* out     = (float*)d_out;

    const int nblocks = (B * 64 + TPB1 - 1) / TPB1;   // one wave per sample
    centerloss_partial<<<nblocks, TPB1, 0, stream>>>(x, labels, centers, partial, B);
    centerloss_final<<<1, TPB2, 0, stream>>>(partial, out, B, B, C);
}